// Round 11
// baseline (34.745 us; speedup 1.0000x reference)
//
#include <hip/hip_runtime.h>

// Problem constants (match reference: B=8, N=8192, D=256, M=2)
#define NN 8192
#define DD 256
#define NH (NN / 2)
#define BB 8
#define RPW 8        // output rows per wave
#define WPB 2        // waves per block (128-thread blocks)
#define DSPLIT 2     // column strips per row (lane = float2)
#define COLS (DD / DSPLIT)               // 128 floats per strip
#define NBLK (BB * (NN / RPW) * DSPLIT / WPB)   // 8192
#define CPX (NBLK / 8)                   // 1024 blocks per XCD chunk (== one batch b)

__device__ __forceinline__ float2 f2_load(const float* p) {
    return *reinterpret_cast<const float2*>(p);
}
__device__ __forceinline__ float2 f2_scale(float s, float2 v) {
    return make_float2(s * v.x, s * v.y);
}
__device__ __forceinline__ float2 f2_fma(float s, float2 v, float2 a) {
    return make_float2(fmaf(s, v.x, a.x), fmaf(s, v.y, a.y));
}

__global__ __launch_bounds__(128) void dhhp_kernel(
    const float* __restrict__ x,
    const float* __restrict__ gl_ii, const float* __restrict__ gl_ij,
    const float* __restrict__ gl_ji, const float* __restrict__ gl_jj,
    const float* __restrict__ gu_ii, const float* __restrict__ gu_ij,
    const float* __restrict__ gu_ji, const float* __restrict__ gu_jj,
    const float* __restrict__ diag, const int* __restrict__ transform,
    float* __restrict__ out)
{
    // XCD-aware swizzle: each XCD gets a contiguous 1024-block chunk == one batch.
    const int bid = blockIdx.x;
    const int swz = (bid & 7) * CPX + (bid >> 3);
    int wid = swz * WPB + (threadIdx.x >> 6);
    wid = __builtin_amdgcn_readfirstlane(wid);       // wave-uniform -> SGPRs
    const int b     = wid >> 11;                     // 2048 waves per batch
    const int rem   = wid & 2047;
    const int j0    = (rem >> 1) << 3;               // jtile * RPW
    const int strip = rem & 1;                       // fastest-varying: L2 halo sharing
    const int col   = strip * COLS + ((threadIdx.x & 63) << 1);  // float2 per lane
    const int tr    = *transform;

    const float* xb  = x    + (size_t)b * NN * DD;
    const float* db  = diag + (size_t)b * NN;
    const float* uii = gu_ii + (size_t)b * (NN - 1);
    const float* uij = gu_ij + (size_t)b * (NN - 1);
    const float* uji = gu_ji + (size_t)b * (NN - 1);
    const float* ujj = gu_jj + (size_t)b * (NN - 1);
    const float* lii = gl_ii + (size_t)b * (NN - 1);
    const float* lij = gl_ij + (size_t)b * (NN - 1);
    const float* lji = gl_ji + (size_t)b * (NN - 1);
    const float* ljj = gl_jj + (size_t)b * (NN - 1);
    float* ob = out + (size_t)b * NN * DD;

    auto permRow = [&](int i) -> int {
        return tr ? ((i < NH) ? (i << 1) : (((i - NH) << 1) | 1)) : i;
    };
    auto loadRowI = [&](int i) -> float2 {           // interior: no clamp
        float2 v = f2_load(xb + (size_t)permRow(i) * DD + col);
        if (!tr) v = f2_scale(db[i], v);
        return v;
    };
    auto loadRowC = [&](int i) -> float2 {           // edge: clamped
        int ic = i < 0 ? 0 : (i > NN - 1 ? NN - 1 : i);
        return loadRowI(ic);
    };
    auto yInner = [&](int i, float2 xm, float2 xc, float2 xp) -> float2 {
        float lo  = uji[i - 1];
        float cjj = ujj[i - 1];
        float dm  = cjj * uii[i];
        float hi  = cjj * uij[i];
        float2 r = f2_scale(lo, xm);
        r = f2_fma(dm, xc, r);
        r = f2_fma(hi, xp, r);
        return r;
    };
    // ghost rows (i<0 / i>N-1 after clamp) produce wrong-but-unused values
    auto yAny = [&](int i, float2 xm, float2 xc, float2 xp) -> float2 {
        int ic = i < 0 ? 0 : (i > NN - 1 ? NN - 1 : i);
        if (ic == 0)      return f2_fma(uii[0], xc, f2_scale(uij[0], xp));
        if (ic == NN - 1) return f2_fma(uji[NN - 2], xm, f2_scale(ujj[NN - 2], xc));
        return yInner(ic, xm, xc, xp);
    };
    auto zInner = [&](int j, float2 ym, float2 yc, float2 yp) -> float2 {
        float ci = lii[j];
        float lo = ci * lji[j - 1];
        float dm = ci * ljj[j - 1];
        float hi = lij[j];
        float2 r = f2_scale(lo, ym);
        r = f2_fma(dm, yc, r);
        r = f2_fma(hi, yp, r);
        return r;
    };
    auto zAny = [&](int j, float2 ym, float2 yc, float2 yp) -> float2 {
        if (j == 0)      return f2_fma(lii[0], yc, f2_scale(lij[0], yp));
        if (j == NN - 1) return f2_fma(lji[NN - 2], ym, f2_scale(ljj[NN - 2], yc));
        return zInner(j, ym, yc, yp);
    };
    auto storeRow = [&](int j, float2 z) {
        int jo;
        float2 o;
        if (tr) { o = f2_scale(db[j], z); jo = j; }
        else    { o = z; jo = (j & 1) ? (NH + (j >> 1)) : (j >> 1); }
        *reinterpret_cast<float2*>(ob + (size_t)jo * DD + col) = o;
    };

    const bool interior = (j0 >= 2) && (j0 <= NN - RPW - 2);

    float2 xr[RPW + 4];   // x[j0-2 .. j0+RPW+1]
    float2 yr[RPW + 2];   // y[j0-1 .. j0+RPW]

    if (interior) {
        #pragma unroll
        for (int t = 0; t < RPW + 4; ++t) xr[t] = loadRowI(j0 - 2 + t);
        #pragma unroll
        for (int t = 0; t < RPW + 2; ++t)
            yr[t] = yInner(j0 - 1 + t, xr[t], xr[t + 1], xr[t + 2]);
        #pragma unroll
        for (int t = 0; t < RPW; ++t)
            storeRow(j0 + t, zInner(j0 + t, yr[t], yr[t + 1], yr[t + 2]));
    } else {
        #pragma unroll
        for (int t = 0; t < RPW + 4; ++t) xr[t] = loadRowC(j0 - 2 + t);
        #pragma unroll
        for (int t = 0; t < RPW + 2; ++t)
            yr[t] = yAny(j0 - 1 + t, xr[t], xr[t + 1], xr[t + 2]);
        #pragma unroll
        for (int t = 0; t < RPW; ++t)
            storeRow(j0 + t, zAny(j0 + t, yr[t], yr[t + 1], yr[t + 2]));
    }
}

extern "C" void kernel_launch(void* const* d_in, const int* in_sizes, int n_in,
                              void* d_out, int out_size, void* d_ws, size_t ws_size,
                              hipStream_t stream) {
    const float* x     = (const float*)d_in[0];
    const float* gl_ii = (const float*)d_in[1];
    const float* gl_ij = (const float*)d_in[2];
    const float* gl_ji = (const float*)d_in[3];
    const float* gl_jj = (const float*)d_in[4];
    const float* gu_ii = (const float*)d_in[5];
    const float* gu_ij = (const float*)d_in[6];
    const float* gu_ji = (const float*)d_in[7];
    const float* gu_jj = (const float*)d_in[8];
    const float* diag  = (const float*)d_in[9];
    const int* transform = (const int*)d_in[10];
    float* out = (float*)d_out;

    dim3 grid(NBLK);      // 8192 blocks, 2 waves each
    dim3 block(128);
    hipLaunchKernelGGL(dhhp_kernel, grid, block, 0, stream,
                       x, gl_ii, gl_ij, gl_ji, gl_jj,
                       gu_ii, gu_ij, gu_ji, gu_jj, diag, transform, out);
}

// Round 13
// 29.533 us; speedup vs baseline: 1.1765x; 1.1765x over previous
//
#include <hip/hip_runtime.h>

// Problem constants (match reference: B=8, N=8192, D=256, M=2)
#define NN 8192
#define DD 256
#define NH (NN / 2)
#define BB 8
#define RPW 8            // output rows per wave
#define WPB 2            // waves per block (128-thread blocks)
#define RPB (RPW * WPB)  // 16 output rows per block
#define LPW 10           // global row-loads per wave (20 rows/block: 1.25x redundancy)
#define NBLK (BB * NN / RPB)   // 4096
#define CPX (NBLK / 8)         // 512 blocks per XCD chunk (== one batch b)

__device__ __forceinline__ float4 f4_load(const float* p) {
    return *reinterpret_cast<const float4*>(p);
}
__device__ __forceinline__ float4 f4_scale(float s, float4 v) {
    return make_float4(s * v.x, s * v.y, s * v.z, s * v.w);
}
__device__ __forceinline__ float4 f4_fma(float s, float4 v, float4 a) {
    return make_float4(fmaf(s, v.x, a.x), fmaf(s, v.y, a.y),
                       fmaf(s, v.z, a.z), fmaf(s, v.w, a.w));
}

__global__ __launch_bounds__(128) void dhhp_kernel(
    const float* __restrict__ x,
    const float* __restrict__ gl_ii, const float* __restrict__ gl_ij,
    const float* __restrict__ gl_ji, const float* __restrict__ gl_jj,
    const float* __restrict__ gu_ii, const float* __restrict__ gu_ij,
    const float* __restrict__ gu_ji, const float* __restrict__ gu_jj,
    const float* __restrict__ diag, const int* __restrict__ transform,
    float* __restrict__ out)
{
    __shared__ float smem[4 * DD];   // 4 exchanged halo rows (4 KB)

    // XCD-aware swizzle: each XCD gets a contiguous 512-block chunk == one batch.
    const int bid = blockIdx.x;
    const int swz = __builtin_amdgcn_readfirstlane((bid & 7) * CPX + (bid >> 3));
    const int b   = swz >> 9;            // 512 blocks per batch
    const int j0b = (swz & 511) << 4;    // block's first output row (16-row tile)
    const int w   = __builtin_amdgcn_readfirstlane(threadIdx.x >> 6);
    const int col = (threadIdx.x & 63) << 2;   // float4 per lane
    const int tr  = *transform;

    const float* xb  = x    + (size_t)b * NN * DD;
    const float* db  = diag + (size_t)b * NN;
    const float* uii = gu_ii + (size_t)b * (NN - 1);
    const float* uij = gu_ij + (size_t)b * (NN - 1);
    const float* uji = gu_ji + (size_t)b * (NN - 1);
    const float* ujj = gu_jj + (size_t)b * (NN - 1);
    const float* lii = gl_ii + (size_t)b * (NN - 1);
    const float* lij = gl_ij + (size_t)b * (NN - 1);
    const float* lji = gl_ji + (size_t)b * (NN - 1);
    const float* ljj = gl_jj + (size_t)b * (NN - 1);
    float* ob = out + (size_t)b * NN * DD;

    // pre-processed (permuted / diag-scaled) row load, clamped
    auto loadRow = [&](int i) -> float4 {
        int ic = i < 0 ? 0 : (i > NN - 1 ? NN - 1 : i);
        int r  = tr ? ((ic < NH) ? (ic << 1) : (((ic - NH) << 1) | 1)) : ic;
        float4 v = f4_load(xb + (size_t)r * DD + col);
        if (!tr) v = f4_scale(db[ic], v);
        return v;
    };

    // ---- register window: rows j0-2 .. j0+9 for this wave (j0 = j0b + 8w) ----
    // wave0 loads rows j0b-2..j0b+7  -> xr[0..9];  receives xr[10],xr[11] via LDS
    // wave1 loads rows j0b+8..j0b+17 -> xr[2..11]; receives xr[0],xr[1]  via LDS
    const int j0 = j0b + (w << 3);
    float4 xr[RPW + 4];

    if (w == 0) {
        #pragma unroll
        for (int q = 0; q < LPW; ++q) xr[q] = loadRow(j0b - 2 + q);
        // share rows j0b+6, j0b+7 (xr[8], xr[9]) -> slots 0,1
        *reinterpret_cast<float4*>(smem + 0 * DD + col) = xr[8];
        *reinterpret_cast<float4*>(smem + 1 * DD + col) = xr[9];
    } else {
        #pragma unroll
        for (int q = 0; q < LPW; ++q) xr[2 + q] = loadRow(j0b + 8 + q);
        // share rows j0b+8, j0b+9 (xr[2], xr[3]) -> slots 2,3
        *reinterpret_cast<float4*>(smem + 2 * DD + col) = xr[2];
        *reinterpret_cast<float4*>(smem + 3 * DD + col) = xr[3];
    }
    __syncthreads();
    if (w == 0) {
        xr[10] = *reinterpret_cast<const float4*>(smem + 2 * DD + col);
        xr[11] = *reinterpret_cast<const float4*>(smem + 3 * DD + col);
    } else {
        xr[0]  = *reinterpret_cast<const float4*>(smem + 0 * DD + col);
        xr[1]  = *reinterpret_cast<const float4*>(smem + 1 * DD + col);
    }

    // ---- compute (identical math to R10) ----
    auto yInner = [&](int i, float4 xm, float4 xc, float4 xp) -> float4 {
        float lo  = uji[i - 1];
        float cjj = ujj[i - 1];
        float dm  = cjj * uii[i];
        float hi  = cjj * uij[i];
        float4 r = f4_scale(lo, xm);
        r = f4_fma(dm, xc, r);
        r = f4_fma(hi, xp, r);
        return r;
    };
    // ghost rows (i<0 / i>N-1 after clamp) produce wrong-but-unused values
    auto yAny = [&](int i, float4 xm, float4 xc, float4 xp) -> float4 {
        int ic = i < 0 ? 0 : (i > NN - 1 ? NN - 1 : i);
        if (ic == 0)      return f4_fma(uii[0], xc, f4_scale(uij[0], xp));
        if (ic == NN - 1) return f4_fma(uji[NN - 2], xm, f4_scale(ujj[NN - 2], xc));
        return yInner(ic, xm, xc, xp);
    };
    auto zInner = [&](int j, float4 ym, float4 yc, float4 yp) -> float4 {
        float ci = lii[j];
        float lo = ci * lji[j - 1];
        float dm = ci * ljj[j - 1];
        float hi = lij[j];
        float4 r = f4_scale(lo, ym);
        r = f4_fma(dm, yc, r);
        r = f4_fma(hi, yp, r);
        return r;
    };
    auto zAny = [&](int j, float4 ym, float4 yc, float4 yp) -> float4 {
        if (j == 0)      return f4_fma(lii[0], yc, f4_scale(lij[0], yp));
        if (j == NN - 1) return f4_fma(lji[NN - 2], ym, f4_scale(ljj[NN - 2], yc));
        return zInner(j, ym, yc, yp);
    };
    auto storeRow = [&](int j, float4 z) {
        int jo;
        float4 o;
        if (tr) { o = f4_scale(db[j], z); jo = j; }
        else    { o = z; jo = (j & 1) ? (NH + (j >> 1)) : (j >> 1); }
        *reinterpret_cast<float4*>(ob + (size_t)jo * DD + col) = o;
    };

    float4 yr[RPW + 2];   // y[j0-1 .. j0+RPW]
    const bool interior = (j0 >= 2) && (j0 <= NN - RPW - 2);

    if (interior) {
        #pragma unroll
        for (int t = 0; t < RPW + 2; ++t)
            yr[t] = yInner(j0 - 1 + t, xr[t], xr[t + 1], xr[t + 2]);
        #pragma unroll
        for (int t = 0; t < RPW; ++t)
            storeRow(j0 + t, zInner(j0 + t, yr[t], yr[t + 1], yr[t + 2]));
    } else {
        #pragma unroll
        for (int t = 0; t < RPW + 2; ++t)
            yr[t] = yAny(j0 - 1 + t, xr[t], xr[t + 1], xr[t + 2]);
        #pragma unroll
        for (int t = 0; t < RPW; ++t)
            storeRow(j0 + t, zAny(j0 + t, yr[t], yr[t + 1], yr[t + 2]));
    }
}

extern "C" void kernel_launch(void* const* d_in, const int* in_sizes, int n_in,
                              void* d_out, int out_size, void* d_ws, size_t ws_size,
                              hipStream_t stream) {
    const float* x     = (const float*)d_in[0];
    const float* gl_ii = (const float*)d_in[1];
    const float* gl_ij = (const float*)d_in[2];
    const float* gl_ji = (const float*)d_in[3];
    const float* gl_jj = (const float*)d_in[4];
    const float* gu_ii = (const float*)d_in[5];
    const float* gu_ij = (const float*)d_in[6];
    const float* gu_ji = (const float*)d_in[7];
    const float* gu_jj = (const float*)d_in[8];
    const float* diag  = (const float*)d_in[9];
    const int* transform = (const int*)d_in[10];
    float* out = (float*)d_out;

    dim3 grid(NBLK);      // 4096 blocks, 2 waves each (same grid as R10; less redundancy)
    dim3 block(128);
    hipLaunchKernelGGL(dhhp_kernel, grid, block, 0, stream,
                       x, gl_ii, gl_ij, gl_ji, gl_jj,
                       gu_ii, gu_ij, gu_ji, gu_jj, diag, transform, out);
}